// Round 10
// baseline (71.865 us; speedup 1.0000x reference)
//
#include <hip/hip_runtime.h>

// skipgram negative-sampling loss, MI355X — round 10.
// Model: stage1 f32 gathers are AT the 512B-granule service floor (~6.6 TB/s,
// R8: 184MB/28us); bf16 halves bytes but serves at 4.8 TB/s and costs a 12us
// convert (R9) -> net wash. Remaining slack = graph structure. This round:
// ONE real dispatch. One wave = one row-pair; all 40 neg-row gathers via 20x
// global_load_lds (1KB each, zero dest VGPRs, all in flight; 20KB LDS/wave,
// 4 blocks/CU -> 160 outstanding instr/CU = same saturation as R8/R9).
// Per-block LDS combine -> 4096 atomicAdds. Graph = memset(4B) + stage1.

constexpr int DIM  = 128;
constexpr int KNEG = 20;

__device__ __forceinline__ float log_sigmoid(float x) {
    // stable: min(x,0) - log1p(exp(-|x|))
    return fminf(x, 0.0f) - log1pf(__expf(-fabsf(x)));
}

typedef __attribute__((address_space(3))) unsigned int       lds_uint;
typedef const __attribute__((address_space(1))) unsigned int glob_uint;

// ---------- single stage: one WAVE = one row-pair ----------
// Chunk j (1KB): row nA[j] (512B) | row nB[j] (512B).
// Writer: lane l (q=l>>5 picks row, s=l&31) -> 16B at chunk + l*16,
//         global src = v_emb + r*DIM + s*4 (same 16B of that row).
// Reader: lane (half=l>>5, l32=l&31) -> float4 at chunk + half*512 + l32*16
//         = dims [4*l32,4*l32+4) of its row. Writer/reader offsets coincide.
__global__ __launch_bounds__(128) void skipgram_fused(
    const float* __restrict__ u_emb, const float* __restrict__ v_emb,
    const int* __restrict__ u_pos, const int* __restrict__ v_pos,
    const int* __restrict__ v_neg, float* __restrict__ out,
    int npairs, float neg_inv_b)
{
    __shared__ float lds_negs[2][KNEG * 256];   // 20KB per wave
    __shared__ float bsum[2];

    const int lane = threadIdx.x & 63;
    const int w    = threadIdx.x >> 6;          // wave slot 0/1
    const int pair = __builtin_amdgcn_readfirstlane(blockIdx.x * 2 + w);
    const int rowA = pair * 2, rowB = rowA + 1;
    const int half = lane >> 5, l32 = lane & 31;

    float pair_loss = 0.0f;

    if (pair < npairs) {
        // ---- uniform scalar index loads ----
        const int upA = u_pos[rowA], upB = u_pos[rowB];
        const int vpA = v_pos[rowA], vpB = v_pos[rowB];
        int nA[KNEG], nB[KNEG];
        const int4* pa = reinterpret_cast<const int4*>(v_neg + (size_t)rowA * KNEG);
        const int4* pb = reinterpret_cast<const int4*>(v_neg + (size_t)rowB * KNEG);
        #pragma unroll
        for (int j = 0; j < 5; ++j) {
            int4 a = pa[j], b = pb[j];
            nA[4*j+0]=a.x; nA[4*j+1]=a.y; nA[4*j+2]=a.z; nA[4*j+3]=a.w;
            nB[4*j+0]=b.x; nB[4*j+1]=b.y; nB[4*j+2]=b.z; nB[4*j+3]=b.w;
        }

        // ---- u / v_pos register loads (issued first, drain with the rest) ----
        const float* urow = u_emb + (size_t)(half ? upB : upA) * DIM;
        const float4 uu = *reinterpret_cast<const float4*>(urow + l32 * 4);
        const float* vrow = v_emb + (size_t)(half ? vpB : vpA) * DIM;
        const float4 vv = *reinterpret_cast<const float4*>(vrow + l32 * 4);

        // ---- 20 async 1KB gathers, all in flight ----
        float* lb = &lds_negs[w][0];
        #pragma unroll
        for (int j = 0; j < KNEG; ++j) {
            const int r = (half == 0) ? nA[j] : nB[j];
            const float* g = v_emb + (size_t)r * DIM + l32 * 4;   // 16B
            __builtin_amdgcn_global_load_lds((glob_uint*)g,
                                             (lds_uint*)(lb + j * 256), 16, 0, 0);
        }

        float pos = fmaf(uu.x, vv.x, fmaf(uu.y, vv.y, fmaf(uu.z, vv.z, uu.w * vv.w)));

        asm volatile("s_waitcnt vmcnt(0)" ::: "memory");
        __builtin_amdgcn_sched_barrier(0);

        float ax = 0.0f, ay = 0.0f, az = 0.0f, aw = 0.0f;
        #pragma unroll
        for (int j = 0; j < KNEG; ++j) {
            const float4 nv = *reinterpret_cast<const float4*>(
                &lds_negs[w][j * 256 + half * 128 + l32 * 4]);
            ax += nv.x; ay += nv.y; az += nv.z; aw += nv.w;
        }
        float neg = fmaf(uu.x, ax, fmaf(uu.y, ay, fmaf(uu.z, az, uu.w * aw)));

        // ---- butterfly within each 32-lane half; lane0=rowA, lane32=rowB ----
        #pragma unroll
        for (int off = 16; off; off >>= 1) {
            pos += __shfl_xor(pos, off);
            neg += __shfl_xor(neg, off);
        }

        float bl = 0.0f;
        if (l32 == 0) bl = log_sigmoid(pos) + log_sigmoid(-neg);
        bl += __shfl_xor(bl, 32);               // lane0: lossA + lossB
        pair_loss = bl;
    }

    // ---- per-block combine (2 waves), one atomic per block ----
    if (lane == 0) bsum[w] = pair_loss;
    __syncthreads();
    if (threadIdx.x == 0)
        atomicAdd(out, (bsum[0] + bsum[1]) * neg_inv_b);
}

// ---------- fallback: B odd (not expected) ----------
__global__ __launch_bounds__(256) void skipgram_f32_kernel(
    const float* __restrict__ u_emb, const float* __restrict__ v_emb,
    const int* __restrict__ u_pos, const int* __restrict__ v_pos,
    const int* __restrict__ v_neg, float* __restrict__ out,
    int B, float neg_inv_b)
{
    const int lane  = threadIdx.x & 63;
    const int wslot = threadIdx.x >> 6;
    const int row   = blockIdx.x * 4 + wslot;

    float contrib = 0.0f;
    if (row < B) {
        const int up = u_pos[row];
        const int vp = v_pos[row];
        int idx[KNEG];
        #pragma unroll
        for (int k = 0; k < KNEG; ++k) idx[k] = v_neg[row * KNEG + k];
        const float2 uu = reinterpret_cast<const float2*>(u_emb + (size_t)up * DIM)[lane];
        const float2 vv = reinterpret_cast<const float2*>(v_emb + (size_t)vp * DIM)[lane];
        float pos = fmaf(uu.x, vv.x, uu.y * vv.y);
        float ax = 0.0f, ay = 0.0f;
        #pragma unroll
        for (int k = 0; k < KNEG; ++k) {
            float2 nv = reinterpret_cast<const float2*>(v_emb + (size_t)idx[k] * DIM)[lane];
            ax += nv.x; ay += nv.y;
        }
        float neg = fmaf(uu.x, ax, uu.y * ay);
        #pragma unroll
        for (int off = 32; off; off >>= 1) {
            pos += __shfl_xor(pos, off);
            neg += __shfl_xor(neg, off);
        }
        contrib = (lane == 0) ? (log_sigmoid(pos) + log_sigmoid(-neg)) : 0.0f;
    }

    __shared__ float wsum[4];
    if (lane == 0) wsum[wslot] = contrib;
    __syncthreads();
    if (threadIdx.x == 0) {
        float s = 0.0f;
        #pragma unroll
        for (int w = 0; w < 4; ++w) s += wsum[w];
        atomicAdd(out, s * neg_inv_b);
    }
}

extern "C" void kernel_launch(void* const* d_in, const int* in_sizes, int n_in,
                              void* d_out, int out_size, void* d_ws, size_t ws_size,
                              hipStream_t stream) {
    const float* u_emb = (const float*)d_in[0];
    const float* v_emb = (const float*)d_in[1];
    const int*   u_pos = (const int*)d_in[2];
    const int*   v_pos = (const int*)d_in[3];
    const int*   v_neg = (const int*)d_in[4];
    float* out = (float*)d_out;

    const int B = in_sizes[2];                  // 16384

    hipMemsetAsync(out, 0, sizeof(float), stream);

    if ((B % 2) == 0) {
        const int pairs  = B / 2;               // 8192 waves
        const int blocks = (pairs + 1) / 2;     // 4096 blocks x 128 thr
        skipgram_fused<<<blocks, 128, 0, stream>>>(
            u_emb, v_emb, u_pos, v_pos, v_neg, out, pairs, -1.0f / (float)B);
    } else {
        const int blocks = (B + 3) / 4;
        skipgram_f32_kernel<<<blocks, 256, 0, stream>>>(
            u_emb, v_emb, u_pos, v_pos, v_neg, out, B, -1.0f / (float)B);
    }
}